// Round 1
// baseline (1786.691 us; speedup 1.0000x reference)
//
#include <hip/hip_runtime.h>
#include <cmath>

namespace {
constexpr int kB = 4;
constexpr int kL = 288;
constexpr int kN = 170;
constexpr int kD = 128;
constexpr int kHeads = 8;
constexpr int kWS = 12;
constexpr int kShift = 6;
constexpr int kHid = 512;
constexpr int kNW = 24;   // kL / kWS
constexpr int kHD = 16;   // kD / kHeads
constexpr float kScale = 0.25f;  // 16^-0.5
constexpr float kEps = 1e-5f;
}

// Kernel A: per (b, window, n): qkv GEMM + windowed MSA + proj + LN1 + residual -> x1
__global__ __launch_bounds__(384) void swin_attn_kernel(
    const float* __restrict__ x,
    const float* __restrict__ qkv_w, const float* __restrict__ qkv_b,
    const float* __restrict__ proj_w, const float* __restrict__ proj_b,
    const float* __restrict__ g1, const float* __restrict__ b1,
    float* __restrict__ x1)
{
  const int blk = blockIdx.x;
  const int n = blk % kN;
  const int bw = blk / kN;
  const int w = bw % kNW;
  const int b = bw / kNW;
  const int tid = threadIdx.x;

  __shared__ float xsT[kD][kWS];          // x tile, transposed (rows 48B, 16B-aligned)
  __shared__ float qkv_s[kWS][3 * kD];    // token-major qkv
  __shared__ float S[kHeads][kWS][kWS];   // scores -> probs (in place)
  __shared__ float aoT[kD][kWS];          // attention out, transposed
  __shared__ float po[kWS][kD];           // proj out, token-major
  __shared__ float mu_s[kWS], rs_s[kWS];

  // ---- load x tile at shifted positions (transposed store) ----
  for (int e = tid; e < kWS * kD; e += 384) {
    const int j = e / kD, d = e % kD;
    const int l = (w * kWS + j - kShift + kL) % kL;
    xsT[d][j] = x[(((size_t)b * kL + l) * kN + n) * kD + d];
  }
  __syncthreads();

  // ---- qkv GEMM: thread owns output column c = tid (384 columns) ----
  {
    const int c = tid;
    float acc[kWS];
    const float bias = qkv_b[c];
#pragma unroll
    for (int j = 0; j < kWS; ++j) acc[j] = bias;
    for (int k = 0; k < kD; ++k) {
      const float wv = qkv_w[k * 384 + c];
      const float4* xr = (const float4*)&xsT[k][0];
      const float4 a0 = xr[0], a1 = xr[1], a2 = xr[2];
      acc[0] += a0.x * wv; acc[1] += a0.y * wv; acc[2]  += a0.z * wv; acc[3]  += a0.w * wv;
      acc[4] += a1.x * wv; acc[5] += a1.y * wv; acc[6]  += a1.z * wv; acc[7]  += a1.w * wv;
      acc[8] += a2.x * wv; acc[9] += a2.y * wv; acc[10] += a2.z * wv; acc[11] += a2.w * wv;
    }
#pragma unroll
    for (int j = 0; j < kWS; ++j) qkv_s[j][c] = acc[j];
  }
  __syncthreads();

  // ---- scores: S[h][i][j] = SCALE * q_i . k_j (+ mask) ----
  for (int e = tid; e < kHeads * kWS * kWS; e += 384) {
    const int h = e / (kWS * kWS);
    const int r = e % (kWS * kWS);
    const int i = r / kWS, j = r % kWS;
    const float* qp = &qkv_s[i][h * kHD];
    const float* kp = &qkv_s[j][kD + h * kHD];
    float s = 0.f;
#pragma unroll
    for (int d = 0; d < kHD; ++d) s += qp[d] * kp[d];
    s *= kScale;
    if (w == 0 && ((i < kShift) != (j < kShift))) s -= 100.f;
    S[h][i][j] = s;
  }
  __syncthreads();

  // ---- softmax over j, per (h,i) row ----
  if (tid < kHeads * kWS) {
    const int h = tid / kWS, i = tid % kWS;
    float m = -1e30f;
#pragma unroll
    for (int j = 0; j < kWS; ++j) m = fmaxf(m, S[h][i][j]);
    float p[kWS];
    float sum = 0.f;
#pragma unroll
    for (int j = 0; j < kWS; ++j) { p[j] = expf(S[h][i][j] - m); sum += p[j]; }
    const float inv = 1.f / sum;
#pragma unroll
    for (int j = 0; j < kWS; ++j) S[h][i][j] = p[j] * inv;
  }
  __syncthreads();

  // ---- PV: ao[i][c] = sum_j P[h(c)][i][j] * v[j][c] ----
  for (int e = tid; e < kWS * kD; e += 384) {
    const int i = e / kD, c = e % kD;
    const int h = c / kHD;
    float s = 0.f;
#pragma unroll
    for (int j = 0; j < kWS; ++j) s += S[h][i][j] * qkv_s[j][2 * kD + c];
    aoT[c][i] = s;
  }
  __syncthreads();

  // ---- proj: c = tid%128 column, g = tid/128 -> tokens 4g..4g+3 ----
  {
    const int c = tid % kD;
    const int g = tid / kD;
    const float bias = proj_b[c];
    float acc0 = bias, acc1 = bias, acc2 = bias, acc3 = bias;
    for (int k = 0; k < kD; ++k) {
      const float wv = proj_w[k * kD + c];
      const float4 a = *(const float4*)&aoT[k][4 * g];
      acc0 += a.x * wv; acc1 += a.y * wv; acc2 += a.z * wv; acc3 += a.w * wv;
    }
    po[4 * g + 0][c] = acc0;
    po[4 * g + 1][c] = acc1;
    po[4 * g + 2][c] = acc2;
    po[4 * g + 3][c] = acc3;
  }
  __syncthreads();

  // ---- LN1 stats per token ----
  if (tid < kWS) {
    const int i = tid;
    float s = 0.f, ss = 0.f;
    for (int c = 0; c < kD; ++c) { const float v = po[i][c]; s += v; ss += v * v; }
    const float mu = s * (1.f / kD);
    const float var = ss * (1.f / kD) - mu * mu;
    mu_s[i] = mu;
    rs_s[i] = rsqrtf(var + kEps);
  }
  __syncthreads();

  // ---- LN1 apply + residual, write to ORIGINAL (unshifted) position ----
  for (int e = tid; e < kWS * kD; e += 384) {
    const int i = e / kD, c = e % kD;
    const int l = (w * kWS + i - kShift + kL) % kL;
    const size_t idx = (((size_t)b * kL + l) * kN + n) * kD + c;
    x1[idx] = (po[i][c] - mu_s[i]) * rs_s[i] * g1[c] + b1[c] + x[idx];
  }
}

// Kernel B: per 16-token tile: fc1 + GELU(exact) + fc2 + LN2 + residual -> out
__global__ __launch_bounds__(512) void swin_mlp_kernel(
    const float* __restrict__ x1,
    const float* __restrict__ fc1_w, const float* __restrict__ fc1_b,
    const float* __restrict__ fc2_w, const float* __restrict__ fc2_b,
    const float* __restrict__ g2, const float* __restrict__ b2,
    float* __restrict__ out)
{
  constexpr int TB = 16;
  const int t0 = blockIdx.x * TB;
  const int tid = threadIdx.x;

  __shared__ float xsT[kD][TB];    // 8 KB (rows 64B)
  __shared__ float hT[kHid][TB];   // 32 KB (rows 64B)
  __shared__ float po[TB][kD];     // 8 KB
  __shared__ float mu_s[TB], rs_s[TB];

  // ---- load x1 tile (transposed) ----
  for (int e = tid; e < TB * kD; e += 512) {
    const int j = e / kD, c = e % kD;
    xsT[c][j] = x1[(size_t)(t0 + j) * kD + c];
  }
  __syncthreads();

  // ---- fc1 + GELU: thread owns hidden column c = tid ----
  {
    const int c = tid;
    float acc[TB];
    const float bias = fc1_b[c];
#pragma unroll
    for (int j = 0; j < TB; ++j) acc[j] = bias;
    for (int k = 0; k < kD; ++k) {
      const float wv = fc1_w[k * kHid + c];
      const float4* xr = (const float4*)&xsT[k][0];
#pragma unroll
      for (int q = 0; q < 4; ++q) {
        const float4 a = xr[q];
        acc[4 * q + 0] += a.x * wv;
        acc[4 * q + 1] += a.y * wv;
        acc[4 * q + 2] += a.z * wv;
        acc[4 * q + 3] += a.w * wv;
      }
    }
#pragma unroll
    for (int j = 0; j < TB; ++j) {
      const float v = acc[j];
      hT[c][j] = 0.5f * v * (1.f + erff(v * 0.70710678118654752f));
    }
  }
  __syncthreads();

  // ---- fc2: c = tid%128 column, g = tid/128 -> tokens 4g..4g+3 ----
  {
    const int c = tid % kD;
    const int g = tid / kD;
    const float bias = fc2_b[c];
    float acc0 = bias, acc1 = bias, acc2 = bias, acc3 = bias;
    for (int k = 0; k < kHid; ++k) {
      const float wv = fc2_w[k * kD + c];
      const float4 a = *(const float4*)&hT[k][4 * g];
      acc0 += a.x * wv; acc1 += a.y * wv; acc2 += a.z * wv; acc3 += a.w * wv;
    }
    po[4 * g + 0][c] = acc0;
    po[4 * g + 1][c] = acc1;
    po[4 * g + 2][c] = acc2;
    po[4 * g + 3][c] = acc3;
  }
  __syncthreads();

  // ---- LN2 stats per token ----
  if (tid < TB) {
    const int j = tid;
    float s = 0.f, ss = 0.f;
    for (int c = 0; c < kD; ++c) { const float v = po[j][c]; s += v; ss += v * v; }
    const float mu = s * (1.f / kD);
    const float var = ss * (1.f / kD) - mu * mu;
    mu_s[j] = mu;
    rs_s[j] = rsqrtf(var + kEps);
  }
  __syncthreads();

  // ---- LN2 apply + residual ----
  for (int e = tid; e < TB * kD; e += 512) {
    const int j = e / kD, c = e % kD;
    const float v = (po[j][c] - mu_s[j]) * rs_s[j] * g2[c] + b2[c] + xsT[c][j];
    out[(size_t)(t0 + j) * kD + c] = v;
  }
}

extern "C" void kernel_launch(void* const* d_in, const int* in_sizes, int n_in,
                              void* d_out, int out_size, void* d_ws, size_t ws_size,
                              hipStream_t stream) {
  const float* x      = (const float*)d_in[0];
  const float* qkv_w  = (const float*)d_in[1];
  const float* qkv_b  = (const float*)d_in[2];
  const float* proj_w = (const float*)d_in[3];
  const float* proj_b = (const float*)d_in[4];
  const float* fc1_w  = (const float*)d_in[5];
  const float* fc1_b  = (const float*)d_in[6];
  const float* fc2_w  = (const float*)d_in[7];
  const float* fc2_b  = (const float*)d_in[8];
  const float* g1     = (const float*)d_in[9];
  const float* b1     = (const float*)d_in[10];
  const float* g2     = (const float*)d_in[11];
  const float* b2     = (const float*)d_in[12];
  float* out = (float*)d_out;
  float* x1  = (float*)d_ws;   // 195840*128*4 B = 100.3 MB scratch

  const int n_groups = kB * kNW * kN;          // 16320
  const int n_tiles  = (kB * kL * kN) / 16;    // 12240

  swin_attn_kernel<<<n_groups, 384, 0, stream>>>(x, qkv_w, qkv_b, proj_w, proj_b,
                                                 g1, b1, x1);
  swin_mlp_kernel<<<n_tiles, 512, 0, stream>>>(x1, fc1_w, fc1_b, fc2_w, fc2_b,
                                               g2, b2, out);
}

// Round 4
// 1082.654 us; speedup vs baseline: 1.6503x; 1.6503x over previous
//
#include <hip/hip_runtime.h>
#include <cmath>

namespace {
constexpr int kB = 4;
constexpr int kL = 288;
constexpr int kN = 170;
constexpr int kD = 128;
constexpr int kHeads = 8;
constexpr int kWS = 12;
constexpr int kShift = 6;
constexpr int kHid = 512;
constexpr int kNW = 24;   // kL / kWS
constexpr int kHD = 16;   // kD / kHeads
constexpr float kScale = 0.25f;  // 16^-0.5
constexpr float kEps = 1e-5f;
constexpr int kTokens = kB * kL * kN;   // 195840
}

typedef __attribute__((ext_vector_type(8))) short bf16x8;
typedef __attribute__((ext_vector_type(4))) short bf16x4;
typedef __attribute__((ext_vector_type(4))) float f32x4;

__device__ inline short f2bf(float f) {
  union { float f; unsigned u; } v; v.f = f;
  const unsigned r = v.u + 0x7fffu + ((v.u >> 16) & 1u);
  return (short)(r >> 16);
}

// ---------------------------------------------------------------------------
// prep: transposed bf16 weights  Wt[c][k] = bf16(W[k][c])
// ---------------------------------------------------------------------------
__global__ __launch_bounds__(256) void prep_weights_kernel(
    const float* __restrict__ fc1_w, const float* __restrict__ fc2_w,
    short* __restrict__ fc1_wt, short* __restrict__ fc2_wt)
{
  const int i = blockIdx.x * 256 + threadIdx.x;
  if (i < kD * kHid) {
    { const int c = i >> 7, k = i & 127; fc1_wt[i] = f2bf(fc1_w[k * kHid + c]); }  // [512][128]
    { const int c = i >> 9, k = i & 511; fc2_wt[i] = f2bf(fc2_w[k * kD + c]); }    // [128][512]
  }
}

// ---------------------------------------------------------------------------
// Kernel A (unchanged): per (b, window, n): qkv + windowed MSA + proj + LN1
// ---------------------------------------------------------------------------
__global__ __launch_bounds__(384) void swin_attn_kernel(
    const float* __restrict__ x,
    const float* __restrict__ qkv_w, const float* __restrict__ qkv_b,
    const float* __restrict__ proj_w, const float* __restrict__ proj_b,
    const float* __restrict__ g1, const float* __restrict__ b1,
    float* __restrict__ x1)
{
  const int blk = blockIdx.x;
  const int n = blk % kN;
  const int bw = blk / kN;
  const int w = bw % kNW;
  const int b = bw / kNW;
  const int tid = threadIdx.x;

  __shared__ float xsT[kD][kWS];
  __shared__ float qkv_s[kWS][3 * kD];
  __shared__ float S[kHeads][kWS][kWS];
  __shared__ float aoT[kD][kWS];
  __shared__ float po[kWS][kD];
  __shared__ float mu_s[kWS], rs_s[kWS];

  for (int e = tid; e < kWS * kD; e += 384) {
    const int j = e / kD, d = e % kD;
    const int l = (w * kWS + j - kShift + kL) % kL;
    xsT[d][j] = x[(((size_t)b * kL + l) * kN + n) * kD + d];
  }
  __syncthreads();

  {
    const int c = tid;
    float acc[kWS];
    const float bias = qkv_b[c];
#pragma unroll
    for (int j = 0; j < kWS; ++j) acc[j] = bias;
    for (int k = 0; k < kD; ++k) {
      const float wv = qkv_w[k * 384 + c];
      const float4* xr = (const float4*)&xsT[k][0];
      const float4 a0 = xr[0], a1 = xr[1], a2 = xr[2];
      acc[0] += a0.x * wv; acc[1] += a0.y * wv; acc[2]  += a0.z * wv; acc[3]  += a0.w * wv;
      acc[4] += a1.x * wv; acc[5] += a1.y * wv; acc[6]  += a1.z * wv; acc[7]  += a1.w * wv;
      acc[8] += a2.x * wv; acc[9] += a2.y * wv; acc[10] += a2.z * wv; acc[11] += a2.w * wv;
    }
#pragma unroll
    for (int j = 0; j < kWS; ++j) qkv_s[j][c] = acc[j];
  }
  __syncthreads();

  for (int e = tid; e < kHeads * kWS * kWS; e += 384) {
    const int h = e / (kWS * kWS);
    const int r = e % (kWS * kWS);
    const int i = r / kWS, j = r % kWS;
    const float* qp = &qkv_s[i][h * kHD];
    const float* kp = &qkv_s[j][kD + h * kHD];
    float s = 0.f;
#pragma unroll
    for (int d = 0; d < kHD; ++d) s += qp[d] * kp[d];
    s *= kScale;
    if (w == 0 && ((i < kShift) != (j < kShift))) s -= 100.f;
    S[h][i][j] = s;
  }
  __syncthreads();

  if (tid < kHeads * kWS) {
    const int h = tid / kWS, i = tid % kWS;
    float m = -1e30f;
#pragma unroll
    for (int j = 0; j < kWS; ++j) m = fmaxf(m, S[h][i][j]);
    float p[kWS];
    float sum = 0.f;
#pragma unroll
    for (int j = 0; j < kWS; ++j) { p[j] = expf(S[h][i][j] - m); sum += p[j]; }
    const float inv = 1.f / sum;
#pragma unroll
    for (int j = 0; j < kWS; ++j) S[h][i][j] = p[j] * inv;
  }
  __syncthreads();

  for (int e = tid; e < kWS * kD; e += 384) {
    const int i = e / kD, c = e % kD;
    const int h = c / kHD;
    float s = 0.f;
#pragma unroll
    for (int j = 0; j < kWS; ++j) s += S[h][i][j] * qkv_s[j][2 * kD + c];
    aoT[c][i] = s;
  }
  __syncthreads();

  {
    const int c = tid % kD;
    const int g = tid / kD;
    const float bias = proj_b[c];
    float acc0 = bias, acc1 = bias, acc2 = bias, acc3 = bias;
    for (int k = 0; k < kD; ++k) {
      const float wv = proj_w[k * kD + c];
      const float4 a = *(const float4*)&aoT[k][4 * g];
      acc0 += a.x * wv; acc1 += a.y * wv; acc2 += a.z * wv; acc3 += a.w * wv;
    }
    po[4 * g + 0][c] = acc0;
    po[4 * g + 1][c] = acc1;
    po[4 * g + 2][c] = acc2;
    po[4 * g + 3][c] = acc3;
  }
  __syncthreads();

  if (tid < kWS) {
    const int i = tid;
    float s = 0.f, ss = 0.f;
    for (int c = 0; c < kD; ++c) { const float v = po[i][c]; s += v; ss += v * v; }
    const float mu = s * (1.f / kD);
    const float var = ss * (1.f / kD) - mu * mu;
    mu_s[i] = mu;
    rs_s[i] = rsqrtf(var + kEps);
  }
  __syncthreads();

  for (int e = tid; e < kWS * kD; e += 384) {
    const int i = e / kD, c = e % kD;
    const int l = (w * kWS + i - kShift + kL) % kL;
    const size_t idx = (((size_t)b * kL + l) * kN + n) * kD + c;
    x1[idx] = (po[i][c] - mu_s[i]) * rs_s[i] * g1[c] + b1[c] + x[idx];
  }
}

// ---------------------------------------------------------------------------
// Kernel B: MFMA MLP. 32 tokens/block, 4 waves.
// fc1 swapped orientation (D[c][t]) -> GELU -> swizzled bf16 h in LDS ->
// fc2 standard orientation -> LN2 + residual.
// ---------------------------------------------------------------------------
__global__ __launch_bounds__(256) void mlp_mfma_kernel(
    const float* __restrict__ x1,
    const short* __restrict__ fc1_wt,   // [512][128] bf16
    const short* __restrict__ fc2_wt,   // [128][512] bf16
    const float* __restrict__ fc1_b, const float* __restrict__ fc2_b,
    const float* __restrict__ g2, const float* __restrict__ b2,
    float* __restrict__ out)
{
  constexpr int TM = 32;
  const int t0 = blockIdx.x * TM;
  const int tid = threadIdx.x;
  const int wave = tid >> 6;
  const int lane = tid & 63;
  const int g = lane >> 4;        // k-chunk / row-group (0..3)
  const int r16 = lane & 15;

  __shared__ short hs[TM * kHid];     // 32 KB bf16, XOR-swizzled rows
  __shared__ float po[TM][kD];        // 16 KB
  __shared__ float mu_s[TM], rs_s[TM];
  char* const hbase = (char*)hs;

  // ---- fc1 B-frags: x1 tokens (fp32 -> bf16). B[k][t]: lane t=r16, k=32s+8g+j
  bf16x8 bfrag[2][4];
#pragma unroll
  for (int tt = 0; tt < 2; ++tt) {
    const float* xp = x1 + (size_t)(t0 + tt * 16 + r16) * kD + g * 8;
#pragma unroll
    for (int s = 0; s < 4; ++s) {
      const float4 lo = *(const float4*)(xp + 32 * s);
      const float4 hi = *(const float4*)(xp + 32 * s + 4);
      bf16x8 bb;
      bb[0] = f2bf(lo.x); bb[1] = f2bf(lo.y); bb[2] = f2bf(lo.z); bb[3] = f2bf(lo.w);
      bb[4] = f2bf(hi.x); bb[5] = f2bf(hi.y); bb[6] = f2bf(hi.z); bb[7] = f2bf(hi.w);
      bfrag[tt][s] = bb;
    }
  }

  // ---- fc1: wave owns hidden cols [wave*128, +128) = 8 M-tiles
  const int c0 = wave * 128;
#pragma unroll 2
  for (int m = 0; m < 8; ++m) {
    const int cbase = c0 + m * 16;
    const short* wp = fc1_wt + (size_t)(cbase + r16) * kD + g * 8;   // A[row=c][k]
    const float4 bias = *(const float4*)(fc1_b + cbase + g * 4);
    f32x4 acc0 = {bias.x, bias.y, bias.z, bias.w};
    f32x4 acc1 = acc0;
#pragma unroll
    for (int s = 0; s < 4; ++s) {
      const bf16x8 a = *(const bf16x8*)(wp + 32 * s);
      acc0 = __builtin_amdgcn_mfma_f32_16x16x32_bf16(a, bfrag[0][s], acc0, 0, 0, 0);
      acc1 = __builtin_amdgcn_mfma_f32_16x16x32_bf16(a, bfrag[1][s], acc1, 0, 0, 0);
    }
    // lane holds h[t = tt*16+r16][cbase + 4g + r], r=0..3  -> GELU -> bf16x4 store
#pragma unroll
    for (int tt = 0; tt < 2; ++tt) {
      const f32x4 v = tt ? acc1 : acc0;
      bf16x4 p;
#pragma unroll
      for (int r = 0; r < 4; ++r) {
        const float z = v[r];
        p[r] = f2bf(0.5f * z * (1.f + erff(z * 0.70710678118654752f)));
      }
      const int t_local = tt * 16 + r16;
      unsigned off = (unsigned)((t_local * kHid + cbase + g * 4) * 2);
      off ^= (unsigned)((t_local & 7) << 4);
      *(bf16x4*)(hbase + off) = p;
    }
  }
  __syncthreads();

  // ---- fc2 standard: D[t][c]; wave owns cols [wave*32, +32) = 2 N-tiles; K=512
  const int n0 = wave * 32;
  f32x4 acc[2][2];   // [tt][nt]
#pragma unroll
  for (int nt = 0; nt < 2; ++nt) {
    const float bv = fc2_b[n0 + nt * 16 + r16];
    acc[0][nt] = {bv, bv, bv, bv};
    acc[1][nt] = acc[0][nt];
  }
#pragma unroll 4
  for (int s = 0; s < 16; ++s) {
    bf16x8 afr[2];
#pragma unroll
    for (int tt = 0; tt < 2; ++tt) {
      const int t_local = tt * 16 + r16;
      unsigned off = (unsigned)((t_local * kHid + s * 32 + g * 8) * 2);
      off ^= (unsigned)((t_local & 7) << 4);
      afr[tt] = *(const bf16x8*)(hbase + off);
    }
#pragma unroll
    for (int nt = 0; nt < 2; ++nt) {
      const bf16x8 bfr = *(const bf16x8*)(fc2_wt + (size_t)(n0 + nt * 16 + r16) * kHid + s * 32 + g * 8);
      acc[0][nt] = __builtin_amdgcn_mfma_f32_16x16x32_bf16(afr[0], bfr, acc[0][nt], 0, 0, 0);
      acc[1][nt] = __builtin_amdgcn_mfma_f32_16x16x32_bf16(afr[1], bfr, acc[1][nt], 0, 0, 0);
    }
  }
#pragma unroll
  for (int tt = 0; tt < 2; ++tt)
#pragma unroll
    for (int nt = 0; nt < 2; ++nt)
#pragma unroll
      for (int r = 0; r < 4; ++r)
        po[tt * 16 + g * 4 + r][n0 + nt * 16 + r16] = acc[tt][nt][r];
  __syncthreads();

  // ---- LN2 stats: 8 threads per token
  {
    const int tok = tid >> 3;
    const int seg = tid & 7;
    float s1 = 0.f, s2 = 0.f;
    const float* pr = &po[tok][seg * 16];
#pragma unroll
    for (int q = 0; q < 16; ++q) { const float v = pr[q]; s1 += v; s2 += v * v; }
#pragma unroll
    for (int d = 1; d < 8; d <<= 1) {
      s1 += __shfl_xor(s1, d);
      s2 += __shfl_xor(s2, d);
    }
    if (seg == 0) {
      const float mu = s1 * (1.f / kD);
      const float var = s2 * (1.f / kD) - mu * mu;
      mu_s[tok] = mu;
      rs_s[tok] = rsqrtf(var + kEps);
    }
  }
  __syncthreads();

  // ---- LN apply + residual + store
  {
    const int tok = tid >> 3;
    const int cb = (tid & 7) * 16;
    const float mu = mu_s[tok], rs = rs_s[tok];
    const size_t gbase = (size_t)(t0 + tok) * kD + cb;
#pragma unroll
    for (int q = 0; q < 16; ++q) {
      const int c = cb + q;
      out[gbase + q] = (po[tok][c] - mu) * rs * g2[c] + b2[c] + x1[gbase + q];
    }
  }
}

extern "C" void kernel_launch(void* const* d_in, const int* in_sizes, int n_in,
                              void* d_out, int out_size, void* d_ws, size_t ws_size,
                              hipStream_t stream) {
  const float* x      = (const float*)d_in[0];
  const float* qkv_w  = (const float*)d_in[1];
  const float* qkv_b  = (const float*)d_in[2];
  const float* proj_w = (const float*)d_in[3];
  const float* proj_b = (const float*)d_in[4];
  const float* fc1_w  = (const float*)d_in[5];
  const float* fc1_b  = (const float*)d_in[6];
  const float* fc2_w  = (const float*)d_in[7];
  const float* fc2_b  = (const float*)d_in[8];
  const float* g1     = (const float*)d_in[9];
  const float* b1     = (const float*)d_in[10];
  const float* g2     = (const float*)d_in[11];
  const float* b2     = (const float*)d_in[12];
  float* out = (float*)d_out;

  float* x1      = (float*)d_ws;                          // 100.27 MB
  short* fc1_wt  = (short*)(x1 + (size_t)kTokens * kD);   // 128 KB
  short* fc2_wt  = fc1_wt + kD * kHid;                    // 128 KB

  const int n_groups = kB * kNW * kN;      // 16320
  const int n_mlp    = kTokens / 32;       // 6120

  prep_weights_kernel<<<(kD * kHid + 255) / 256, 256, 0, stream>>>(fc1_w, fc2_w, fc1_wt, fc2_wt);
  swin_attn_kernel<<<n_groups, 384, 0, stream>>>(x, qkv_w, qkv_b, proj_w, proj_b,
                                                 g1, b1, x1);
  mlp_mfma_kernel<<<n_mlp, 256, 0, stream>>>(x1, fc1_wt, fc2_wt, fc1_b, fc2_b,
                                             g2, b2, out);
}

// Round 5
// 681.589 us; speedup vs baseline: 2.6214x; 1.5884x over previous
//
#include <hip/hip_runtime.h>
#include <cmath>

namespace {
constexpr int kB = 4;
constexpr int kL = 288;
constexpr int kN = 170;
constexpr int kD = 128;
constexpr int kHeads = 8;
constexpr int kWS = 12;
constexpr int kShift = 6;
constexpr int kHid = 512;
constexpr int kNW = 24;   // kL / kWS
constexpr int kHD = 16;   // kD / kHeads
constexpr float kScale = 0.25f;  // 16^-0.5
constexpr float kEps = 1e-5f;
constexpr int kTokens = kB * kL * kN;   // 195840
constexpr int kGroups = kB * kNW * kN;  // 16320
}

typedef __attribute__((ext_vector_type(8))) short bf16x8;
typedef __attribute__((ext_vector_type(4))) short bf16x4;
typedef __attribute__((ext_vector_type(4))) float f32x4;

__device__ inline short f2bf(float f) {
  union { float f; unsigned u; } v; v.f = f;
  const unsigned r = v.u + 0x7fffu + ((v.u >> 16) & 1u);
  return (short)(r >> 16);
}
__device__ inline float bf2f(short s) {
  union { unsigned u; float f; } v;
  v.u = ((unsigned)(unsigned short)s) << 16;
  return v.f;
}

// ---------------------------------------------------------------------------
// prep: transposed bf16 weights.  attn pointers may be null (fallback path).
// ---------------------------------------------------------------------------
__global__ __launch_bounds__(256) void prep_weights_kernel(
    const float* __restrict__ fc1_w, const float* __restrict__ fc2_w,
    const float* __restrict__ qkv_w, const float* __restrict__ proj_w,
    short* __restrict__ fc1_wt, short* __restrict__ fc2_wt,
    short* __restrict__ qkv_wt, short* __restrict__ proj_wt)
{
  const int i = blockIdx.x * 256 + threadIdx.x;   // grid 256 -> 65536 threads
  if (i < kD * kHid) {
    { const int c = i >> 7, k = i & 127; fc1_wt[i] = f2bf(fc1_w[k * kHid + c]); }  // [512][128]
    { const int c = i >> 9, k = i & 511; fc2_wt[i] = f2bf(fc2_w[k * kD + c]); }    // [128][512]
  }
  if (qkv_wt != nullptr) {
    if (i < 384 * kD) { const int c = i >> 7, k = i & 127; qkv_wt[i]  = f2bf(qkv_w[k * 384 + c]); }  // [384][128]
    if (i < kD * kD)  { const int c = i >> 7, k = i & 127; proj_wt[i] = f2bf(proj_w[k * kD + c]); }  // [128][128]
  }
}

// ---------------------------------------------------------------------------
// qkv MFMA: [195840 x 128] @ [128 x 384] in WINDOWED row order.
// Swapped orientation D[c][t] (verified fc1 recipe). 32 rows/block, 4 waves.
// ---------------------------------------------------------------------------
__global__ __launch_bounds__(256) void qkv_mfma_kernel(
    const float* __restrict__ x,
    const short* __restrict__ qkv_wt,   // [384][128] bf16
    const float* __restrict__ qkv_b,
    short* __restrict__ qkvb)           // [195840][384] bf16, windowed order
{
  const int t0 = blockIdx.x * 32;
  const int tid = threadIdx.x;
  const int wave = tid >> 6, lane = tid & 63;
  const int g = lane >> 4, r16 = lane & 15;

  // B-frags: gather x rows at shifted/windowed positions, fp32 -> bf16
  bf16x8 bfrag[2][4];
#pragma unroll
  for (int tt = 0; tt < 2; ++tt) {
    const int row = t0 + tt * 16 + r16;
    const int grp = row / 12, j = row - grp * 12;
    const int n = grp % kN;
    const int bw = grp / kN;
    const int w = bw % kNW, b = bw / kNW;
    int l = w * kWS + j - kShift; if (l < 0) l += kL;
    const float* xp = x + (((size_t)b * kL + l) * kN + n) * kD + g * 8;
#pragma unroll
    for (int s = 0; s < 4; ++s) {
      const float4 lo = *(const float4*)(xp + 32 * s);
      const float4 hi = *(const float4*)(xp + 32 * s + 4);
      bf16x8 bb;
      bb[0] = f2bf(lo.x); bb[1] = f2bf(lo.y); bb[2] = f2bf(lo.z); bb[3] = f2bf(lo.w);
      bb[4] = f2bf(hi.x); bb[5] = f2bf(hi.y); bb[6] = f2bf(hi.z); bb[7] = f2bf(hi.w);
      bfrag[tt][s] = bb;
    }
  }

  const int c0 = wave * 96;          // wave owns 96 of 384 output cols
#pragma unroll 2
  for (int m = 0; m < 6; ++m) {
    const int cbase = c0 + m * 16;
    const short* wp = qkv_wt + (size_t)(cbase + r16) * kD + g * 8;
    const float4 bv = *(const float4*)(qkv_b + cbase + g * 4);
    f32x4 acc0 = {bv.x, bv.y, bv.z, bv.w};
    f32x4 acc1 = acc0;
#pragma unroll
    for (int s = 0; s < 4; ++s) {
      const bf16x8 a = *(const bf16x8*)(wp + 32 * s);
      acc0 = __builtin_amdgcn_mfma_f32_16x16x32_bf16(a, bfrag[0][s], acc0, 0, 0, 0);
      acc1 = __builtin_amdgcn_mfma_f32_16x16x32_bf16(a, bfrag[1][s], acc1, 0, 0, 0);
    }
#pragma unroll
    for (int tt = 0; tt < 2; ++tt) {
      const f32x4 v = tt ? acc1 : acc0;
      bf16x4 pk;
#pragma unroll
      for (int r = 0; r < 4; ++r) pk[r] = f2bf(v[r]);
      const int row = t0 + tt * 16 + r16;
      *(bf16x4*)(qkvb + (size_t)row * 384 + cbase + g * 4) = pk;
    }
  }
}

// ---------------------------------------------------------------------------
// attn core: 4 windows (48 tokens)/block. VALU attention + MFMA proj + LN1.
// LDS: qs [48][384] bf16 (linear) | ao [48][128] bf16 (swizzled) |
//      po [48][128] fp32 (swizzled, unioned over dead qs region).
// ---------------------------------------------------------------------------
__global__ __launch_bounds__(256) void attn_core_kernel(
    const short* __restrict__ qkvb,
    const short* __restrict__ proj_wt,  // [128][128] bf16
    const float* __restrict__ proj_b,
    const float* __restrict__ x,
    const float* __restrict__ g1, const float* __restrict__ b1,
    float* __restrict__ x1)
{
  constexpr int NB = 4;
  constexpr int NT = NB * kWS;          // 48
  const int blk = blockIdx.x;
  const int tid = threadIdx.x;

  __shared__ __align__(16) char smem[NT * 384 * 2 + NT * kD * 2];  // 36864 + 12288
  short* const qs  = (short*)smem;                // [48][384] bf16, linear
  char*  const aoc = smem + NT * 384 * 2;         // [48][128] bf16, swizzled
  char*  const poc = smem;                        // [48][128] fp32, swizzled (reuse)
  __shared__ float mu_s[NT], rs_s[NT];

  // ---- stage the block's qkv tile (contiguous, coalesced) ----
  {
    const bf16x8* src = (const bf16x8*)(qkvb + (size_t)blk * NT * 384);
    bf16x8* dst = (bf16x8*)qs;
#pragma unroll
    for (int e = 0; e < 9; ++e) dst[e * 256 + tid] = src[e * 256 + tid];
  }
  __syncthreads();

  // ---- attention: task = (local group g, head h, q-row i) ----
  for (int task = tid; task < NB * 96; task += 256) {
    const int g = task / 96;
    const int rem = task - g * 96;
    const int h = rem / 12;
    const int i = rem - h * 12;
    const int gg = blk * NB + g;
    const bool edge = ((gg / kN) % kNW) == 0;   // window 0 has the shift mask
    const short* base = qs + g * 12 * 384;

    const bf16x8 q0 = *(const bf16x8*)(base + i * 384 + h * 16);
    const bf16x8 q1 = *(const bf16x8*)(base + i * 384 + h * 16 + 8);
    float q[16];
#pragma unroll
    for (int d = 0; d < 8; ++d) { q[d] = bf2f(q0[d]) * kScale; q[8 + d] = bf2f(q1[d]) * kScale; }

    float p[12];
    float m = -1e30f;
#pragma unroll
    for (int j = 0; j < 12; ++j) {
      const bf16x8 k0 = *(const bf16x8*)(base + j * 384 + 128 + h * 16);
      const bf16x8 k1 = *(const bf16x8*)(base + j * 384 + 128 + h * 16 + 8);
      float s = 0.f;
#pragma unroll
      for (int d = 0; d < 8; ++d) s += q[d] * bf2f(k0[d]) + q[8 + d] * bf2f(k1[d]);
      if (edge && ((i < 6) != (j < 6))) s -= 100.f;
      p[j] = s;
      m = fmaxf(m, s);
    }
    float sum = 0.f;
#pragma unroll
    for (int j = 0; j < 12; ++j) { p[j] = expf(p[j] - m); sum += p[j]; }
    const float inv = 1.f / sum;

    float acc[16];
#pragma unroll
    for (int d = 0; d < 16; ++d) acc[d] = 0.f;
#pragma unroll
    for (int j = 0; j < 12; ++j) {
      const bf16x8 v0 = *(const bf16x8*)(base + j * 384 + 256 + h * 16);
      const bf16x8 v1 = *(const bf16x8*)(base + j * 384 + 256 + h * 16 + 8);
      const float pj = p[j] * inv;
#pragma unroll
      for (int d = 0; d < 8; ++d) { acc[d] += pj * bf2f(v0[d]); acc[8 + d] += pj * bf2f(v1[d]); }
    }
    const int t = g * 12 + i;
    bf16x8 o0, o1;
#pragma unroll
    for (int d = 0; d < 8; ++d) { o0[d] = f2bf(acc[d]); o1[d] = f2bf(acc[8 + d]); }
    const unsigned swz = (unsigned)((t & 7) << 4);
    *(bf16x8*)(aoc + (((unsigned)(t * 256 + h * 32)) ^ swz)) = o0;
    *(bf16x8*)(aoc + (((unsigned)(t * 256 + h * 32 + 16)) ^ swz)) = o1;
  }
  __syncthreads();

  // ---- proj MFMA: D[c][t], wave owns 32 cols; 3 token-tiles; K=128 ----
  {
    const int wave = tid >> 6, lane = tid & 63;
    const int g4 = lane >> 4, r16 = lane & 15;
    const int cb0 = wave * 32;
    f32x4 acc[2][3];
#pragma unroll
    for (int mm = 0; mm < 2; ++mm) {
      const float4 bv = *(const float4*)(proj_b + cb0 + mm * 16 + g4 * 4);
      const f32x4 bi = {bv.x, bv.y, bv.z, bv.w};
      acc[mm][0] = bi; acc[mm][1] = bi; acc[mm][2] = bi;
    }
#pragma unroll
    for (int s = 0; s < 4; ++s) {
      bf16x8 afr[2], bfr[3];
#pragma unroll
      for (int mm = 0; mm < 2; ++mm)
        afr[mm] = *(const bf16x8*)(proj_wt + (size_t)(cb0 + mm * 16 + r16) * kD + s * 32 + g4 * 8);
#pragma unroll
      for (int tt = 0; tt < 3; ++tt) {
        const int t = tt * 16 + r16;
        const unsigned boff = ((unsigned)(t * 256 + s * 64 + g4 * 16)) ^ ((unsigned)((t & 7) << 4));
        bfr[tt] = *(const bf16x8*)(aoc + boff);
      }
#pragma unroll
      for (int mm = 0; mm < 2; ++mm)
#pragma unroll
        for (int tt = 0; tt < 3; ++tt)
          acc[mm][tt] = __builtin_amdgcn_mfma_f32_16x16x32_bf16(afr[mm], bfr[tt], acc[mm][tt], 0, 0, 0);
    }
    // write po over dead qs region (no one reads qs anymore; ao untouched)
#pragma unroll
    for (int mm = 0; mm < 2; ++mm)
#pragma unroll
      for (int tt = 0; tt < 3; ++tt) {
        const int t = tt * 16 + r16;
        const int c = cb0 + mm * 16 + g4 * 4;
        const unsigned poff = ((unsigned)(t * 512 + c * 4)) ^ ((unsigned)((t & 7) << 4));
        *(f32x4*)(poc + poff) = acc[mm][tt];
      }
  }
  __syncthreads();

  // ---- LN1 stats: 4 lanes per token ----
  {
    const int tok = tid >> 2;
    const int seg = tid & 3;
    if (tok < NT) {
      const unsigned swz = (unsigned)((tok & 7) << 4);
      float s1 = 0.f, s2 = 0.f;
#pragma unroll
      for (int qd = 0; qd < 32; ++qd) {
        const int c = seg * 32 + qd;
        const float v = *(const float*)(poc + (((unsigned)(tok * 512 + c * 4)) ^ swz));
        s1 += v; s2 += v * v;
      }
#pragma unroll
      for (int d = 1; d < 4; d <<= 1) { s1 += __shfl_xor(s1, d); s2 += __shfl_xor(s2, d); }
      if (seg == 0) {
        const float mu = s1 * (1.f / kD);
        const float var = s2 * (1.f / kD) - mu * mu;
        mu_s[tok] = mu;
        rs_s[tok] = rsqrtf(var + kEps);
      }
    }
  }
  __syncthreads();

  // ---- LN1 apply + residual, scatter to original token positions ----
  for (int e = tid; e < NT * kD; e += 256) {
    const int t = e >> 7, c = e & 127;
    const float v = *(const float*)(poc +
        (((unsigned)(t * 512 + c * 4)) ^ ((unsigned)((t & 7) << 4))));
    const int gg = blk * NB + t / 12;
    const int j = t - (t / 12) * 12;
    const int n = gg % kN;
    const int bw = gg / kN;
    const int w = bw % kNW, b = bw / kNW;
    int l = w * kWS + j - kShift; if (l < 0) l += kL;
    const size_t idx = (((size_t)b * kL + l) * kN + n) * kD + c;
    x1[idx] = (v - mu_s[t]) * rs_s[t] * g1[c] + b1[c] + x[idx];
  }
}

// ---------------------------------------------------------------------------
// FALLBACK kernel (round-4 verified fp32 attention) — used if ws too small.
// ---------------------------------------------------------------------------
__global__ __launch_bounds__(384) void swin_attn_kernel(
    const float* __restrict__ x,
    const float* __restrict__ qkv_w, const float* __restrict__ qkv_b,
    const float* __restrict__ proj_w, const float* __restrict__ proj_b,
    const float* __restrict__ g1, const float* __restrict__ b1,
    float* __restrict__ x1)
{
  const int blk = blockIdx.x;
  const int n = blk % kN;
  const int bw = blk / kN;
  const int w = bw % kNW;
  const int b = bw / kNW;
  const int tid = threadIdx.x;

  __shared__ float xsT[kD][kWS];
  __shared__ float qkv_s[kWS][3 * kD];
  __shared__ float S[kHeads][kWS][kWS];
  __shared__ float aoT[kD][kWS];
  __shared__ float po[kWS][kD];
  __shared__ float mu_s[kWS], rs_s[kWS];

  for (int e = tid; e < kWS * kD; e += 384) {
    const int j = e / kD, d = e % kD;
    const int l = (w * kWS + j - kShift + kL) % kL;
    xsT[d][j] = x[(((size_t)b * kL + l) * kN + n) * kD + d];
  }
  __syncthreads();

  {
    const int c = tid;
    float acc[kWS];
    const float bias = qkv_b[c];
#pragma unroll
    for (int j = 0; j < kWS; ++j) acc[j] = bias;
    for (int k = 0; k < kD; ++k) {
      const float wv = qkv_w[k * 384 + c];
      const float4* xr = (const float4*)&xsT[k][0];
      const float4 a0 = xr[0], a1 = xr[1], a2 = xr[2];
      acc[0] += a0.x * wv; acc[1] += a0.y * wv; acc[2]  += a0.z * wv; acc[3]  += a0.w * wv;
      acc[4] += a1.x * wv; acc[5] += a1.y * wv; acc[6]  += a1.z * wv; acc[7]  += a1.w * wv;
      acc[8] += a2.x * wv; acc[9] += a2.y * wv; acc[10] += a2.z * wv; acc[11] += a2.w * wv;
    }
#pragma unroll
    for (int j = 0; j < kWS; ++j) qkv_s[j][c] = acc[j];
  }
  __syncthreads();

  for (int e = tid; e < kHeads * kWS * kWS; e += 384) {
    const int h = e / (kWS * kWS);
    const int r = e % (kWS * kWS);
    const int i = r / kWS, j = r % kWS;
    const float* qp = &qkv_s[i][h * kHD];
    const float* kp = &qkv_s[j][kD + h * kHD];
    float s = 0.f;
#pragma unroll
    for (int d = 0; d < kHD; ++d) s += qp[d] * kp[d];
    s *= kScale;
    if (w == 0 && ((i < kShift) != (j < kShift))) s -= 100.f;
    S[h][i][j] = s;
  }
  __syncthreads();

  if (tid < kHeads * kWS) {
    const int h = tid / kWS, i = tid % kWS;
    float m = -1e30f;
#pragma unroll
    for (int j = 0; j < kWS; ++j) m = fmaxf(m, S[h][i][j]);
    float p[kWS];
    float sum = 0.f;
#pragma unroll
    for (int j = 0; j < kWS; ++j) { p[j] = expf(S[h][i][j] - m); sum += p[j]; }
    const float inv = 1.f / sum;
#pragma unroll
    for (int j = 0; j < kWS; ++j) S[h][i][j] = p[j] * inv;
  }
  __syncthreads();

  for (int e = tid; e < kWS * kD; e += 384) {
    const int i = e / kD, c = e % kD;
    const int h = c / kHD;
    float s = 0.f;
#pragma unroll
    for (int j = 0; j < kWS; ++j) s += S[h][i][j] * qkv_s[j][2 * kD + c];
    aoT[c][i] = s;
  }
  __syncthreads();

  {
    const int c = tid % kD;
    const int g = tid / kD;
    const float bias = proj_b[c];
    float acc0 = bias, acc1 = bias, acc2 = bias, acc3 = bias;
    for (int k = 0; k < kD; ++k) {
      const float wv = proj_w[k * kD + c];
      const float4 a = *(const float4*)&aoT[k][4 * g];
      acc0 += a.x * wv; acc1 += a.y * wv; acc2 += a.z * wv; acc3 += a.w * wv;
    }
    po[4 * g + 0][c] = acc0;
    po[4 * g + 1][c] = acc1;
    po[4 * g + 2][c] = acc2;
    po[4 * g + 3][c] = acc3;
  }
  __syncthreads();

  if (tid < kWS) {
    const int i = tid;
    float s = 0.f, ss = 0.f;
    for (int c = 0; c < kD; ++c) { const float v = po[i][c]; s += v; ss += v * v; }
    const float mu = s * (1.f / kD);
    const float var = ss * (1.f / kD) - mu * mu;
    mu_s[i] = mu;
    rs_s[i] = rsqrtf(var + kEps);
  }
  __syncthreads();

  for (int e = tid; e < kWS * kD; e += 384) {
    const int i = e / kD, c = e % kD;
    const int l = (w * kWS + i - kShift + kL) % kL;
    const size_t idx = (((size_t)b * kL + l) * kN + n) * kD + c;
    x1[idx] = (po[i][c] - mu_s[i]) * rs_s[i] * g1[c] + b1[c] + x[idx];
  }
}

// ---------------------------------------------------------------------------
// MFMA MLP (verified round 4, unchanged)
// ---------------------------------------------------------------------------
__global__ __launch_bounds__(256) void mlp_mfma_kernel(
    const float* __restrict__ x1,
    const short* __restrict__ fc1_wt,   // [512][128] bf16
    const short* __restrict__ fc2_wt,   // [128][512] bf16
    const float* __restrict__ fc1_b, const float* __restrict__ fc2_b,
    const float* __restrict__ g2, const float* __restrict__ b2,
    float* __restrict__ out)
{
  constexpr int TM = 32;
  const int t0 = blockIdx.x * TM;
  const int tid = threadIdx.x;
  const int wave = tid >> 6;
  const int lane = tid & 63;
  const int g = lane >> 4;
  const int r16 = lane & 15;

  __shared__ short hs[TM * kHid];
  __shared__ float po[TM][kD];
  __shared__ float mu_s[TM], rs_s[TM];
  char* const hbase = (char*)hs;

  bf16x8 bfrag[2][4];
#pragma unroll
  for (int tt = 0; tt < 2; ++tt) {
    const float* xp = x1 + (size_t)(t0 + tt * 16 + r16) * kD + g * 8;
#pragma unroll
    for (int s = 0; s < 4; ++s) {
      const float4 lo = *(const float4*)(xp + 32 * s);
      const float4 hi = *(const float4*)(xp + 32 * s + 4);
      bf16x8 bb;
      bb[0] = f2bf(lo.x); bb[1] = f2bf(lo.y); bb[2] = f2bf(lo.z); bb[3] = f2bf(lo.w);
      bb[4] = f2bf(hi.x); bb[5] = f2bf(hi.y); bb[6] = f2bf(hi.z); bb[7] = f2bf(hi.w);
      bfrag[tt][s] = bb;
    }
  }

  const int c0 = wave * 128;
#pragma unroll 2
  for (int m = 0; m < 8; ++m) {
    const int cbase = c0 + m * 16;
    const short* wp = fc1_wt + (size_t)(cbase + r16) * kD + g * 8;
    const float4 bias = *(const float4*)(fc1_b + cbase + g * 4);
    f32x4 acc0 = {bias.x, bias.y, bias.z, bias.w};
    f32x4 acc1 = acc0;
#pragma unroll
    for (int s = 0; s < 4; ++s) {
      const bf16x8 a = *(const bf16x8*)(wp + 32 * s);
      acc0 = __builtin_amdgcn_mfma_f32_16x16x32_bf16(a, bfrag[0][s], acc0, 0, 0, 0);
      acc1 = __builtin_amdgcn_mfma_f32_16x16x32_bf16(a, bfrag[1][s], acc1, 0, 0, 0);
    }
#pragma unroll
    for (int tt = 0; tt < 2; ++tt) {
      const f32x4 v = tt ? acc1 : acc0;
      bf16x4 p;
#pragma unroll
      for (int r = 0; r < 4; ++r) {
        const float z = v[r];
        p[r] = f2bf(0.5f * z * (1.f + erff(z * 0.70710678118654752f)));
      }
      const int t_local = tt * 16 + r16;
      unsigned off = (unsigned)((t_local * kHid + cbase + g * 4) * 2);
      off ^= (unsigned)((t_local & 7) << 4);
      *(bf16x4*)(hbase + off) = p;
    }
  }
  __syncthreads();

  const int n0 = wave * 32;
  f32x4 acc[2][2];
#pragma unroll
  for (int nt = 0; nt < 2; ++nt) {
    const float bv = fc2_b[n0 + nt * 16 + r16];
    acc[0][nt] = {bv, bv, bv, bv};
    acc[1][nt] = acc[0][nt];
  }
#pragma unroll 4
  for (int s = 0; s < 16; ++s) {
    bf16x8 afr[2];
#pragma unroll
    for (int tt = 0; tt < 2; ++tt) {
      const int t_local = tt * 16 + r16;
      unsigned off = (unsigned)((t_local * kHid + s * 32 + g * 8) * 2);
      off ^= (unsigned)((t_local & 7) << 4);
      afr[tt] = *(const bf16x8*)(hbase + off);
    }
#pragma unroll
    for (int nt = 0; nt < 2; ++nt) {
      const bf16x8 bfr = *(const bf16x8*)(fc2_wt + (size_t)(n0 + nt * 16 + r16) * kHid + s * 32 + g * 8);
      acc[0][nt] = __builtin_amdgcn_mfma_f32_16x16x32_bf16(afr[0], bfr, acc[0][nt], 0, 0, 0);
      acc[1][nt] = __builtin_amdgcn_mfma_f32_16x16x32_bf16(afr[1], bfr, acc[1][nt], 0, 0, 0);
    }
  }
#pragma unroll
  for (int tt = 0; tt < 2; ++tt)
#pragma unroll
    for (int nt = 0; nt < 2; ++nt)
#pragma unroll
      for (int r = 0; r < 4; ++r)
        po[tt * 16 + g * 4 + r][n0 + nt * 16 + r16] = acc[tt][nt][r];
  __syncthreads();

  {
    const int tok = tid >> 3;
    const int seg = tid & 7;
    float s1 = 0.f, s2 = 0.f;
    const float* pr = &po[tok][seg * 16];
#pragma unroll
    for (int q = 0; q < 16; ++q) { const float v = pr[q]; s1 += v; s2 += v * v; }
#pragma unroll
    for (int d = 1; d < 8; d <<= 1) {
      s1 += __shfl_xor(s1, d);
      s2 += __shfl_xor(s2, d);
    }
    if (seg == 0) {
      const float mu = s1 * (1.f / kD);
      const float var = s2 * (1.f / kD) - mu * mu;
      mu_s[tok] = mu;
      rs_s[tok] = rsqrtf(var + kEps);
    }
  }
  __syncthreads();

  {
    const int tok = tid >> 3;
    const int cb = (tid & 7) * 16;
    const float mu = mu_s[tok], rs = rs_s[tok];
    const size_t gbase = (size_t)(t0 + tok) * kD + cb;
#pragma unroll
    for (int q = 0; q < 16; ++q) {
      const int c = cb + q;
      out[gbase + q] = (po[tok][c] - mu) * rs * g2[c] + b2[c] + x1[gbase + q];
    }
  }
}

extern "C" void kernel_launch(void* const* d_in, const int* in_sizes, int n_in,
                              void* d_out, int out_size, void* d_ws, size_t ws_size,
                              hipStream_t stream) {
  const float* x      = (const float*)d_in[0];
  const float* qkv_w  = (const float*)d_in[1];
  const float* qkv_b  = (const float*)d_in[2];
  const float* proj_w = (const float*)d_in[3];
  const float* proj_b = (const float*)d_in[4];
  const float* fc1_w  = (const float*)d_in[5];
  const float* fc1_b  = (const float*)d_in[6];
  const float* fc2_w  = (const float*)d_in[7];
  const float* fc2_b  = (const float*)d_in[8];
  const float* g1     = (const float*)d_in[9];
  const float* b1     = (const float*)d_in[10];
  const float* g2     = (const float*)d_in[11];
  const float* b2     = (const float*)d_in[12];
  float* out = (float*)d_out;

  float* x1 = (float*)d_ws;   // 100.27 MB
  const size_t need_new = (size_t)kTokens * kD * 4          // x1
                        + (size_t)kTokens * 384 * 2         // qkvb
                        + (size_t)(384 * kD + kD * kD + kHid * kD + kD * kHid) * 2;

  if (ws_size >= need_new) {
    short* qkvb    = (short*)(x1 + (size_t)kTokens * kD);
    short* qkv_wt  = qkvb + (size_t)kTokens * 384;
    short* proj_wt = qkv_wt + 384 * kD;
    short* fc1_wt  = proj_wt + kD * kD;
    short* fc2_wt  = fc1_wt + kHid * kD;

    prep_weights_kernel<<<256, 256, 0, stream>>>(fc1_w, fc2_w, qkv_w, proj_w,
                                                 fc1_wt, fc2_wt, qkv_wt, proj_wt);
    qkv_mfma_kernel<<<kTokens / 32, 256, 0, stream>>>(x, qkv_wt, qkv_b, qkvb);
    attn_core_kernel<<<kGroups / 4, 256, 0, stream>>>(qkvb, proj_wt, proj_b, x,
                                                      g1, b1, x1);
    mlp_mfma_kernel<<<kTokens / 32, 256, 0, stream>>>(x1, fc1_wt, fc2_wt, fc1_b,
                                                      fc2_b, g2, b2, out);
  } else {
    // fallback: round-4 verified pipeline (needs only ~100.5 MB)
    short* fc1_wt = (short*)(x1 + (size_t)kTokens * kD);
    short* fc2_wt = fc1_wt + kD * kHid;
    prep_weights_kernel<<<256, 256, 0, stream>>>(fc1_w, fc2_w, nullptr, nullptr,
                                                 fc1_wt, fc2_wt, nullptr, nullptr);
    swin_attn_kernel<<<kGroups, 384, 0, stream>>>(x, qkv_w, qkv_b, proj_w, proj_b,
                                                  g1, b1, x1);
    mlp_mfma_kernel<<<kTokens / 32, 256, 0, stream>>>(x1, fc1_wt, fc2_wt, fc1_b,
                                                      fc2_b, g2, b2, out);
  }
}